// Round 4
// baseline (89.698 us; speedup 1.0000x reference)
//
#include <hip/hip_runtime.h>

// TensorProduct: out[b, seg[n], c] += CG[n] * x1[b, M1[n], c] * x2[b, M2[n], c]
// B=128, NUM_M=25, C=128, fp32.
// v4: NSPLIT=8 (512-thr blocks) -> 4 blocks/CU x 8 waves = 32 waves/CU (HW max,
// 8 waves/SIMD) to hide the s_load->gather->FMA chain. Index path stays SGPR-uniform
// (ballot-derived bounds + readfirstlane wave id -> M1/M2/cg are s_loads).
// Packed math: v_pk_mul_f32 + v_pk_fma_f32 cut per-iter VALU 8 -> ~6.

#define NUM_M  25
#define B_SZ   128
#define C_DIM  128
#define C4     (C_DIM / 4)   // 32 float4 chunks
#define NSPLIT 8             // waves per block, n-interleave factor

typedef float f32x2 __attribute__((ext_vector_type(2)));

__device__ __forceinline__ int wave_lower_bound(const int* __restrict__ seg,
                                                int nnz, int key) {
    const int lane = threadIdx.x & 63;
    int lo = 0, hi = nnz;            // invariant: seg[lo-1] < key <= seg[hi] (sentinels)
    while (hi > lo) {
        const int len = hi - lo;
        const int S = (len + 63) >> 6;          // ceil(len/64)
        const int idx = lo + lane * S;
        bool pred = false;
        if (idx < hi) pred = (seg[idx] < key);
        const unsigned long long bal = __ballot(pred);
        const int c = __popcll(bal);            // first sample >= key is sample #c
        if (c == 0) { hi = lo; break; }         // seg[lo] >= key -> answer = lo
        int nhi = lo + c * S;
        if (nhi > hi) nhi = hi;
        lo = lo + (c - 1) * S + 1;
        hi = nhi;
    }
    return lo;
}

__global__ __launch_bounds__(512) void tp_kernel(
    const float* __restrict__ x1, const float* __restrict__ x2,
    const float* __restrict__ cg, const int* __restrict__ M1,
    const int* __restrict__ M2, const int* __restrict__ seg,
    int nnz, float* __restrict__ out) {

    const int m    = blockIdx.x;          // 0..24  (output M index)
    const int bp   = blockIdx.y;          // 0..63  (batch pair)
    const int tid  = threadIdx.x;         // 0..511
    const int lane = tid & 63;
    // wave id, forced into an SGPR so the n-loop stays scalar
    const int w    = __builtin_amdgcn_readfirstlane(tid >> 6);
    const int b    = bp * 2 + (lane >> 5);
    const int c4   = lane & 31;

    // Each wave computes its own bounds (ballot-derived -> SGPR-uniform; L2-hot)
    const int lo = wave_lower_bound(seg, nnz, m);
    const int hi = wave_lower_bound(seg, nnz, m + 1);

    const float4* __restrict__ x1t = ((const float4*)x1) + b * (NUM_M * C4) + c4;
    const float4* __restrict__ x2t = ((const float4*)x2) + b * (NUM_M * C4) + c4;

    f32x2 acc01 = {0.f, 0.f};
    f32x2 acc23 = {0.f, 0.f};

#pragma unroll 4
    for (int n = lo + w; n < hi; n += NSPLIT) {
        const int   m1 = M1[n];           // wave-uniform -> s_load
        const int   m2 = M2[n];
        const float wt = cg[n];
        const float4 a  = x1t[m1 * C4];   // coalesced 16B/lane, cache-hot
        const float4 bb = x2t[m2 * C4];
        f32x2 a01 = {a.x, a.y},  a23 = {a.z, a.w};
        f32x2 b01 = {bb.x, bb.y}, b23 = {bb.z, bb.w};
        f32x2 w2  = {wt, wt};
        f32x2 t01, t23;
        asm("v_pk_mul_f32 %0, %1, %2" : "=v"(t01) : "v"(a01), "v"(b01));
        asm("v_pk_mul_f32 %0, %1, %2" : "=v"(t23) : "v"(a23), "v"(b23));
        asm("v_pk_fma_f32 %0, %1, %2, %0" : "+v"(acc01) : "v"(t01), "v"(w2));
        asm("v_pk_fma_f32 %0, %1, %2, %0" : "+v"(acc23) : "v"(t23), "v"(w2));
    }

    // Cross-wave reduction in LDS (waves 1..7 publish, wave 0 sums + stores)
    __shared__ float4 red[NSPLIT - 1][64];
    if (w > 0) {
        float4 v;
        v.x = acc01.x; v.y = acc01.y; v.z = acc23.x; v.w = acc23.y;
        red[w - 1][lane] = v;
    }
    __syncthreads();
    if (w == 0) {
        float4 acc;
        acc.x = acc01.x; acc.y = acc01.y; acc.z = acc23.x; acc.w = acc23.y;
#pragma unroll
        for (int k = 0; k < NSPLIT - 1; ++k) {
            const float4 r = red[k][lane];
            acc.x += r.x; acc.y += r.y; acc.z += r.z; acc.w += r.w;
        }
        ((float4*)out)[b * (NUM_M * C4) + m * C4 + c4] = acc;
    }
}

extern "C" void kernel_launch(void* const* d_in, const int* in_sizes, int n_in,
                              void* d_out, int out_size, void* d_ws, size_t ws_size,
                              hipStream_t stream) {
    const float* x1  = (const float*)d_in[0];
    const float* x2  = (const float*)d_in[1];
    const float* cg  = (const float*)d_in[2];
    const int*   M1  = (const int*)d_in[3];
    const int*   M2  = (const int*)d_in[4];
    const int*   seg = (const int*)d_in[5];
    const int    nnz = in_sizes[2];
    float* out = (float*)d_out;

    dim3 grid(NUM_M, B_SZ / 2);   // 25 x 64 blocks, 8 waves each
    tp_kernel<<<grid, 512, 0, stream>>>(x1, x2, cg, M1, M2, seg, nnz, out);
}

// Round 5
// 82.633 us; speedup vs baseline: 1.0855x; 1.0855x over previous
//
#include <hip/hip_runtime.h>

// TensorProduct: out[b, seg[n], c] += CG[n] * x1[b, M1[n], c] * x2[b, M2[n], c]
// B=128, NUM_M=25, C=128, fp32.
// v5: v3 base (4 waves/block, SGPR-uniform index path) + m1-RUN HOISTING.
// Pattern is sorted (m_out, M1, M2) -> contiguous equal-M1 runs (avg ~10).
// x1 row loaded once per run; run end found by 64-lane ballot over M1[n..n+63]
// (one coalesced 256B load, no serial scalar scan). Waves take CONTIGUOUS
// quarters of the segment so runs stay intact. Cuts L1 gather traffic ~45%
// (v3 was ~84% of the 256B/clk/CU L1 pipe -> that was the bottleneck).

#define NUM_M  25
#define B_SZ   128
#define C_DIM  128
#define C4     (C_DIM / 4)   // 32 float4 chunks
#define NSPLIT 4             // waves per block (contiguous segment quarters)

__device__ __forceinline__ int wave_lower_bound(const int* __restrict__ seg,
                                                int nnz, int key) {
    const int lane = threadIdx.x & 63;
    int lo = 0, hi = nnz;            // invariant: seg[lo-1] < key <= seg[hi] (sentinels)
    while (hi > lo) {
        const int len = hi - lo;
        const int S = (len + 63) >> 6;          // ceil(len/64)
        const int idx = lo + lane * S;
        bool pred = false;
        if (idx < hi) pred = (seg[idx] < key);
        const unsigned long long bal = __ballot(pred);
        const int c = __popcll(bal);            // first sample >= key is sample #c
        if (c == 0) { hi = lo; break; }         // seg[lo] >= key -> answer = lo
        int nhi = lo + c * S;
        if (nhi > hi) nhi = hi;
        lo = lo + (c - 1) * S + 1;
        hi = nhi;
    }
    return lo;
}

__global__ __launch_bounds__(256) void tp_kernel(
    const float* __restrict__ x1, const float* __restrict__ x2,
    const float* __restrict__ cg, const int* __restrict__ M1,
    const int* __restrict__ M2, const int* __restrict__ seg,
    int nnz, float* __restrict__ out) {

    const int m    = blockIdx.x;          // 0..24  (output M index)
    const int bp   = blockIdx.y;          // 0..63  (batch pair)
    const int tid  = threadIdx.x;         // 0..255
    const int lane = tid & 63;
    const int w    = __builtin_amdgcn_readfirstlane(tid >> 6);  // wave id, SGPR
    const int b    = bp * 2 + (lane >> 5);
    const int c4   = lane & 31;

    // Per-wave segment bounds (ballot-derived -> SGPR-uniform; L2-hot)
    const int lo = wave_lower_bound(seg, nnz, m);
    const int hi = wave_lower_bound(seg, nnz, m + 1);
    const int L  = hi - lo;

    // Contiguous quarter for this wave (keeps M1-runs intact)
    int       n    = lo + (L * w) / NSPLIT;
    const int nhiw = lo + (L * (w + 1)) / NSPLIT;

    const float4* __restrict__ x1t = ((const float4*)x1) + b * (NUM_M * C4) + c4;
    const float4* __restrict__ x2t = ((const float4*)x2) + b * (NUM_M * C4) + c4;

    float4 acc = make_float4(0.f, 0.f, 0.f, 0.f);

    while (n < nhiw) {
        const int m1 = __builtin_amdgcn_readfirstlane(M1[n]);
        const float4 a = x1t[m1 * C4];          // one x1 row per run

        // Wave-parallel run-end detection: lanes probe M1[n..n+63]
        int idx = n + lane;
        if (idx > nnz - 1) idx = nnz - 1;
        const bool same = (n + lane < nhiw) && (M1[idx] == m1);
        const unsigned long long bal = __ballot(same);
        int rl = (bal == ~0ull) ? 64 : __builtin_ctzll(~bal);  // lane 0 always true
        rl = __builtin_amdgcn_readfirstlane(rl);
        const int e = n + rl;                   // run end (uniform, >= n+1)

#pragma unroll 4
        for (int k = n; k < e; ++k) {
            const float wt = cg[k];             // uniform -> s_load
            const int   m2 = M2[k];             // uniform -> s_load
            const float4 bb = x2t[m2 * C4];     // the only per-entry gather now
            acc.x = fmaf(wt * a.x, bb.x, acc.x);
            acc.y = fmaf(wt * a.y, bb.y, acc.y);
            acc.z = fmaf(wt * a.z, bb.z, acc.z);
            acc.w = fmaf(wt * a.w, bb.w, acc.w);
        }
        n = e;
    }

    // Cross-wave reduction in LDS (waves 1..3 publish, wave 0 sums + stores)
    __shared__ float4 red[NSPLIT - 1][64];
    if (w > 0) red[w - 1][lane] = acc;
    __syncthreads();
    if (w == 0) {
#pragma unroll
        for (int k = 0; k < NSPLIT - 1; ++k) {
            const float4 r = red[k][lane];
            acc.x += r.x; acc.y += r.y; acc.z += r.z; acc.w += r.w;
        }
        ((float4*)out)[b * (NUM_M * C4) + m * C4 + c4] = acc;
    }
}

extern "C" void kernel_launch(void* const* d_in, const int* in_sizes, int n_in,
                              void* d_out, int out_size, void* d_ws, size_t ws_size,
                              hipStream_t stream) {
    const float* x1  = (const float*)d_in[0];
    const float* x2  = (const float*)d_in[1];
    const float* cg  = (const float*)d_in[2];
    const int*   M1  = (const int*)d_in[3];
    const int*   M2  = (const int*)d_in[4];
    const int*   seg = (const int*)d_in[5];
    const int    nnz = in_sizes[2];
    float* out = (float*)d_out;

    dim3 grid(NUM_M, B_SZ / 2);   // 25 x 64 blocks, 4 waves each
    tp_kernel<<<grid, 256, 0, stream>>>(x1, x2, cg, M1, M2, seg, nnz, out);
}